// Round 11
// baseline (261.350 us; speedup 1.0000x reference)
//
#include <hip/hip_runtime.h>
#include <hip/hip_bf16.h>
#include <math.h>

// Problem constants
#define F_DIM 2048
#define B_DIM 2
#define H_DIM 1024
#define N_HEADS 16
#define E_DIM 64
#define D3 3072          // 3*H
#define M_DIM 4096       // F*B

typedef __hip_bfloat16 bf16;
typedef __attribute__((ext_vector_type(8))) __bf16 bf16x8;
typedef __attribute__((ext_vector_type(8))) unsigned short u16x8;
typedef __attribute__((ext_vector_type(4))) float f32x4;

// float -> bf16 bits, round-to-nearest-even
static __device__ __forceinline__ unsigned short f2bf(float f) {
    unsigned u = __float_as_uint(f);
    return (unsigned short)((u + 0x7FFFu + ((u >> 16) & 1u)) >> 16);
}
static __device__ __forceinline__ float bf2f(unsigned short b) {
    return __uint_as_float(((unsigned)b) << 16);
}

// async global->LDS, 16B per lane; lds ptr must be wave-uniform base
static __device__ __forceinline__ void glds16(const unsigned short* g, unsigned short* l) {
    __builtin_amdgcn_global_load_lds((const __attribute__((address_space(1))) unsigned int*)g,
                                     (__attribute__((address_space(3))) unsigned int*)l,
                                     16, 0, 0);
}

// ---------------------------------------------------------------------------
// Fused prep (R10-proven)
// ---------------------------------------------------------------------------
__global__ __launch_bounds__(256) void prep_kernel(const float* __restrict__ q_input,
                                                   const void* __restrict__ mask,
                                                   const float* __restrict__ w_qkv,
                                                   const float* __restrict__ w_out,
                                                   const float* __restrict__ b_out,
                                                   unsigned short* __restrict__ qin_bf,
                                                   unsigned short* __restrict__ wqkv_bt,
                                                   unsigned short* __restrict__ wout_bt,
                                                   unsigned* __restrict__ mbits,
                                                   float* __restrict__ bout_dst) {
    __shared__ float sh[32 * 33];
    const int bid = blockIdx.x;
    const int tid = threadIdx.x;

    if (bid < 2048) {                       // convert
        int i = (bid * 256 + tid) * 8;
        float4 a = *(const float4*)&q_input[i];
        float4 b = *(const float4*)&q_input[i + 4];
        u16x8 o;
        o[0] = f2bf(a.x); o[1] = f2bf(a.y); o[2] = f2bf(a.z); o[3] = f2bf(a.w);
        o[4] = f2bf(b.x); o[5] = f2bf(b.y); o[6] = f2bf(b.z); o[7] = f2bf(b.w);
        *(u16x8*)&qin_bf[i] = o;
    } else if (bid < 6144) {                // transposes
        const float* in; unsigned short* out; int R, C, bx, by;
        if (bid < 5120) { int idx = bid - 2048; in = w_qkv; out = wqkv_bt; R = 1024; C = 3072; bx = idx % 96; by = idx / 96; }
        else            { int idx = bid - 5120; in = w_out; out = wout_bt; R = 1024; C = 1024; bx = idx % 32; by = idx / 32; }
        float (*t)[33] = (float(*)[33])sh;
        const int c0 = bx * 32, r0 = by * 32;
        const int lc = tid & 31, lr = tid >> 5;
        #pragma unroll
        for (int i = 0; i < 4; ++i) {
            int r = lr + i * 8;
            t[r][lc] = in[(size_t)(r0 + r) * C + c0 + lc];
        }
        __syncthreads();
        #pragma unroll
        for (int i = 0; i < 4; ++i) {
            int r = lr + i * 8;
            out[(size_t)(c0 + r) * R + r0 + lc] = f2bf(t[lc][r]);
        }
    } else if (bid < 7168) {                // mask pack with inline detect
        int* shi = (int*)sh;
        int v = ((const int*)mask)[tid] & ~1;
        unsigned long long bal = __ballot(v != 0);
        if ((tid & 63) == 0) shi[tid >> 6] = (bal != 0) ? 1 : 0;
        __syncthreads();
        const int byte_mode = shi[0] | shi[1] | shi[2] | shi[3];
        int w = (bid - 6144) * 256 + tid;
        size_t base = (size_t)w * 32;
        unsigned out = 0;
        if (byte_mode) {
            const unsigned char* mu = (const unsigned char*)mask;
            #pragma unroll
            for (int j = 0; j < 32; ++j) out |= (mu[base + j] ? 1u : 0u) << j;
        } else {
            const int* mi = (const int*)mask;
            #pragma unroll
            for (int j = 0; j < 32; ++j) out |= (mi[base + j] ? 1u : 0u) << j;
        }
        mbits[w] = out;
    } else {                                // b_out copy
        int h = (bid - 7168) * 256 + tid;
        if (h < H_DIM) bout_dst[h] = b_out[h];
    }
}

// --------------------- fallback prep kernels (R9-proven) -------------------
__global__ void detect_mask_kernel(const int* __restrict__ mask_words, int* __restrict__ flag) {
    __shared__ int red[256];
    int v = mask_words[threadIdx.x];
    red[threadIdx.x] = v & ~1;
    __syncthreads();
    for (int s = 128; s > 0; s >>= 1) {
        if (threadIdx.x < s) red[threadIdx.x] |= red[threadIdx.x + s];
        __syncthreads();
    }
    if (threadIdx.x == 0) *flag = (red[0] != 0) ? 1 : 0;
}

__global__ void pack_mask_kernel(const int* __restrict__ mi, const unsigned char* __restrict__ mu,
                                 const int* __restrict__ flag, unsigned* __restrict__ bits) {
    int w = blockIdx.x * 256 + threadIdx.x;
    size_t base = (size_t)w * 32;
    unsigned out = 0;
    if (*flag) {
        #pragma unroll
        for (int j = 0; j < 32; ++j) out |= (mu[base + j] ? 1u : 0u) << j;
    } else {
        #pragma unroll
        for (int j = 0; j < 32; ++j) out |= (mi[base + j] ? 1u : 0u) << j;
    }
    bits[w] = out;
}

__global__ __launch_bounds__(256) void convert_kernel(const float* __restrict__ in,
                                                      unsigned short* __restrict__ out) {
    int i = (blockIdx.x * 256 + threadIdx.x) * 8;
    float4 a = *(const float4*)&in[i];
    float4 b = *(const float4*)&in[i + 4];
    u16x8 o;
    o[0] = f2bf(a.x); o[1] = f2bf(a.y); o[2] = f2bf(a.z); o[3] = f2bf(a.w);
    o[4] = f2bf(b.x); o[5] = f2bf(b.y); o[6] = f2bf(b.z); o[7] = f2bf(b.w);
    *(u16x8*)&out[i] = o;
}

__global__ __launch_bounds__(256) void transpose_bf16_kernel(const float* __restrict__ in,
                                                             unsigned short* __restrict__ out,
                                                             int R, int C) {
    __shared__ float t[32][33];
    const int c0 = blockIdx.x * 32, r0 = blockIdx.y * 32;
    const int lc = threadIdx.x & 31, lr = threadIdx.x >> 5;
    #pragma unroll
    for (int i = 0; i < 4; ++i) {
        int r = lr + i * 8;
        t[r][lc] = in[(size_t)(r0 + r) * C + c0 + lc];
    }
    __syncthreads();
    #pragma unroll
    for (int i = 0; i < 4; ++i) {
        int r = lr + i * 8;
        out[(size_t)(c0 + r) * R + r0 + lc] = f2bf(t[lc][r]);
    }
}

__global__ void bout_copy_kernel(const float* __restrict__ b_out, float* __restrict__ dst) {
    int h = blockIdx.x * 256 + threadIdx.x;
    if (h < H_DIM) dst[h] = b_out[h];
}

// ---------------------------------------------------------------------------
// m97-style bf16 MFMA GEMM, B-transposed input, tile BM x BN (mult of 64).
// ---------------------------------------------------------------------------
template<int BM, int BN, bool ADD_BIAS, bool OUT_BF16>
__global__ __launch_bounds__(256) void gemm_bt_kernel(const unsigned short* __restrict__ A,
                                                      const unsigned short* __restrict__ Bt,
                                                      const float* __restrict__ bias,
                                                      void* __restrict__ Cout, int Nc) {
    __shared__ unsigned short Ald[BM * 32];
    __shared__ unsigned short Bld[BN * 32];
    constexpr int WM = BM / 2, WN = BN / 2;
    constexpr int MI = WM / 16, NI = WN / 16;
    constexpr int ACH = BM * 4;
    constexpr int TCH = (BM + BN) * 4;
    const int tid = threadIdx.x;
    const int wave = tid >> 6;
    const int lane = tid & 63;
    const int quad = lane >> 4;
    const int l16 = lane & 15;
    const int wm = (wave & 1) * WM;
    const int wn = (wave >> 1) * WN;
    const int m0 = blockIdx.y * BM;
    const int n0 = blockIdx.x * BN;

    f32x4 acc[MI][NI];
    #pragma unroll
    for (int i = 0; i < MI; ++i)
        #pragma unroll
        for (int j = 0; j < NI; ++j) acc[i][j] = (f32x4){0.f, 0.f, 0.f, 0.f};

    for (int k0 = 0; k0 < 1024; k0 += 32) {
        __syncthreads();
        #pragma unroll
        for (int rr = 0; rr < TCH / 256; ++rr) {
            const int chunk = rr * 256 + tid;
            const int wbase = (rr * 256 + wave * 64) * 8;
            if (chunk < ACH) {
                const int row = chunk >> 2, ko = (chunk & 3) * 8;
                glds16(&A[(size_t)(m0 + row) * 1024 + k0 + ko], &Ald[wbase]);
            } else {
                const int c2 = chunk - ACH;
                const int row = c2 >> 2, ko = (c2 & 3) * 8;
                glds16(&Bt[(size_t)(n0 + row) * 1024 + k0 + ko], &Bld[wbase - ACH * 8]);
            }
        }
        __syncthreads();

        bf16x8 af[MI], bfr[NI];
        #pragma unroll
        for (int i = 0; i < MI; ++i)
            af[i] = *(const bf16x8*)&Ald[(wm + i * 16 + l16) * 32 + quad * 8];
        #pragma unroll
        for (int j = 0; j < NI; ++j)
            bfr[j] = *(const bf16x8*)&Bld[(wn + j * 16 + l16) * 32 + quad * 8];
        #pragma unroll
        for (int mi = 0; mi < MI; ++mi)
            #pragma unroll
            for (int ni = 0; ni < NI; ++ni)
                acc[mi][ni] = __builtin_amdgcn_mfma_f32_16x16x32_bf16(af[mi], bfr[ni], acc[mi][ni], 0, 0, 0);
    }

    #pragma unroll
    for (int ni = 0; ni < NI; ++ni) {
        const int col = n0 + wn + ni * 16 + l16;
        const float bv = ADD_BIAS ? bias[col] : 0.f;
        #pragma unroll
        for (int mi = 0; mi < MI; ++mi) {
            const int rowb = m0 + wm + mi * 16 + quad * 4;
            #pragma unroll
            for (int r = 0; r < 4; ++r) {
                float v = acc[mi][ni][r] + bv;
                if (OUT_BF16) ((unsigned short*)Cout)[(size_t)(rowb + r) * Nc + col] = f2bf(v);
                else          ((float*)Cout)[(size_t)(rowb + r) * Nc + col] = v;
            }
        }
    }
}

// ---------------------------------------------------------------------------
// MFMA flash attention (R10-proven body), optionally t-split across
// blockIdx.z. Fixed-max softmax => partials (O, l) combine by ADDITION.
// SPLIT=false: full t range, normalized bf16 ctx out (R10 path).
// SPLIT=true : t in [z*1024, z*1024+1024), un-normalized bf16 O-partial +
//              fp32 l-partial out; combine_kernel finishes.
// ---------------------------------------------------------------------------
#define LSTR 72        // LDS row stride (elements) for K, Vt, and P
template<bool SPLIT>
__global__ __launch_bounds__(512) void attn_mfma_kernel(const bf16* __restrict__ qkv_,
                                                        const unsigned* __restrict__ mbits,
                                                        unsigned short* __restrict__ outp,
                                                        float* __restrict__ lpart) {
    __shared__ unsigned short K_lds[64 * LSTR];        // [t][e]      9216 B
    __shared__ unsigned short Vt_lds[64 * LSTR];       // [e][slot]   9216 B
    __shared__ unsigned short P_lds[128 * LSTR];       // [row][slot] 18432 B

    const unsigned short* qkv = (const unsigned short*)qkv_;
    const int tid = threadIdx.x;
    const int wave = tid >> 6;          // 0..7
    const int lane = tid & 63;
    const int quad = lane >> 4;
    const int l16 = lane & 15;
    const int f0 = blockIdx.x * 128;
    const int b = blockIdx.y >> 4;
    const int n = blockIdx.y & 15;
    const int head = n * 192;
    const int tbase = SPLIT ? blockIdx.z * 1024 : 0;
    const int tend  = SPLIT ? tbase + 1024 : F_DIM;

    // Q fragments [ks] (A layout): rows f0 + wave*16 + l16
    bf16x8 qf[2];
    #pragma unroll
    for (int ks = 0; ks < 2; ++ks) {
        int f = f0 + wave * 16 + l16;
        qf[ks] = *(const bf16x8*)&qkv[(size_t)(f * B_DIM + b) * D3 + head + ks * 32 + quad * 8];
    }

    f32x4 O[4];
    #pragma unroll
    for (int ec = 0; ec < 4; ++ec) O[ec] = (f32x4){0.f, 0.f, 0.f, 0.f};
    float lsum[4] = {0.f, 0.f, 0.f, 0.f};

    unsigned short* Pw = P_lds + wave * 16 * LSTR;
    const float c_exp = 0.18033688011112042f;   // 0.125 * log2(e)

    for (int t0 = tbase; t0 < tend; t0 += 64) {
        __syncthreads();   // previous tile's LDS reads complete

        // stage K tile [64][64] row-major: 512 chunks, 1/thread
        {
            int tr = tid >> 3, e0 = (tid & 7) * 8;
            u16x8 kv = *(const u16x8*)&qkv[(size_t)((t0 + tr) * B_DIM + b) * D3 + head + 64 + e0];
            *(u16x8*)&K_lds[tr * LSTR + e0] = kv;
        }
        // stage V transposed with (t, t+16) interleave: slot h*32+2u(+o).
        if (tid < 256) {
            int u = tid & 15, h = (tid >> 4) & 1, e0 = (tid >> 5) * 8;
            int ta = t0 + h * 32 + u;
            u16x8 v0 = *(const u16x8*)&qkv[(size_t)(ta * B_DIM + b) * D3 + head + 128 + e0];
            u16x8 v1 = *(const u16x8*)&qkv[(size_t)((ta + 16) * B_DIM + b) * D3 + head + 128 + e0];
            #pragma unroll
            for (int j = 0; j < 8; ++j) {
                unsigned pk = (unsigned)v0[j] | ((unsigned)v1[j] << 16);
                *(unsigned*)&Vt_lds[(e0 + j) * LSTR + h * 32 + 2 * u] = pk;
            }
        }
        __syncthreads();   // staging visible

        // S = Q . K^T  [16 x 64] per wave; S[ck] covers t = ck*16 + l16
        f32x4 S[4];
        #pragma unroll
        for (int ck = 0; ck < 4; ++ck) S[ck] = (f32x4){0.f, 0.f, 0.f, 0.f};
        #pragma unroll
        for (int ck = 0; ck < 4; ++ck) {
            bf16x8 kb0 = *(const bf16x8*)&K_lds[(ck * 16 + l16) * LSTR + quad * 8];
            bf16x8 kb1 = *(const bf16x8*)&K_lds[(ck * 16 + l16) * LSTR + 32 + quad * 8];
            S[ck] = __builtin_amdgcn_mfma_f32_16x16x32_bf16(qf[0], kb0, S[ck], 0, 0, 0);
            S[ck] = __builtin_amdgcn_mfma_f32_16x16x32_bf16(qf[1], kb1, S[ck], 0, 0, 0);
        }

        // fixed-max softmax + packed P writes (R10-proven):
        // (p0,p1) -> slots (2*l16, 2*l16+1); (p2,p3) -> +32.
        #pragma unroll
        for (int r = 0; r < 4; ++r) {
            const int row = quad * 4 + r;            // within wave's 16 rows
            const int f = f0 + wave * 16 + row;
            uint2 wb = *(const uint2*)&mbits[((size_t)b * F_DIM + f) * 64 + (t0 >> 5)];
            float p[4];
            #pragma unroll
            for (int ck = 0; ck < 4; ++ck) {
                unsigned wsel = (ck & 2) ? wb.y : wb.x;
                int bit = ((ck & 1) << 4) + l16;
                float pv = __builtin_amdgcn_exp2f(S[ck][r] * c_exp);
                p[ck] = ((wsel >> bit) & 1u) ? pv : 0.f;
            }
            lsum[r] += (p[0] + p[1]) + (p[2] + p[3]);
            unsigned pk01 = (unsigned)f2bf(p[0]) | ((unsigned)f2bf(p[1]) << 16);
            unsigned pk23 = (unsigned)f2bf(p[2]) | ((unsigned)f2bf(p[3]) << 16);
            *(unsigned*)&Pw[row * LSTR + 2 * l16] = pk01;
            *(unsigned*)&Pw[row * LSTR + 32 + 2 * l16] = pk23;
        }

        // O += P . V  (both operands traverse slots in identical order)
        #pragma unroll
        for (int ks = 0; ks < 2; ++ks) {
            bf16x8 pa = *(const bf16x8*)&Pw[l16 * LSTR + ks * 32 + quad * 8];
            #pragma unroll
            for (int ec = 0; ec < 4; ++ec) {
                bf16x8 vb = *(const bf16x8*)&Vt_lds[(ec * 16 + l16) * LSTR + ks * 32 + quad * 8];
                O[ec] = __builtin_amdgcn_mfma_f32_16x16x32_bf16(pa, vb, O[ec], 0, 0, 0);
            }
        }
    }

    // epilogue
    #pragma unroll
    for (int r = 0; r < 4; ++r) {
        float l = lsum[r];
        #pragma unroll
        for (int d = 1; d < 16; d <<= 1) l += __shfl_xor(l, d);
        const int f = f0 + wave * 16 + quad * 4 + r;
        if (SPLIT) {
            unsigned short* Op = outp + (size_t)blockIdx.z * 4194304;
            #pragma unroll
            for (int ec = 0; ec < 4; ++ec)
                Op[(size_t)(f * B_DIM + b) * H_DIM + n * 64 + ec * 16 + l16] = f2bf(O[ec][r]);
            if (l16 == 0) lpart[blockIdx.z * 65536 + (f * B_DIM + b) * 16 + n] = l;
        } else {
            const float inv = 1.0f / l;
            #pragma unroll
            for (int ec = 0; ec < 4; ++ec)
                outp[(size_t)(f * B_DIM + b) * H_DIM + n * 64 + ec * 16 + l16] = f2bf(O[ec][r] * inv);
        }
    }
}

// ---------------------------------------------------------------------------
// Combine: ctx = (O0 + O1) / (l0 + l1). 4194304 elems, 8 per thread.
// ---------------------------------------------------------------------------
__global__ __launch_bounds__(256) void combine_kernel(const unsigned short* __restrict__ Opart,
                                                      const float* __restrict__ lpart,
                                                      unsigned short* __restrict__ ctx) {
    int i = (blockIdx.x * 256 + threadIdx.x) * 8;
    int row = i >> 10;                   // f*B+b
    int n = (i & 1023) >> 6;
    float inv = 1.0f / (lpart[row * 16 + n] + lpart[65536 + row * 16 + n]);
    u16x8 a = *(const u16x8*)&Opart[i];
    u16x8 c = *(const u16x8*)&Opart[4194304 + i];
    u16x8 o;
    #pragma unroll
    for (int j = 0; j < 8; ++j) o[j] = f2bf((bf2f(a[j]) + bf2f(c[j])) * inv);
    *(u16x8*)&ctx[i] = o;
}

// ---------------------------------------------------------------------------
extern "C" void kernel_launch(void* const* d_in, const int* in_sizes, int n_in,
                              void* d_out, int out_size, void* d_ws, size_t ws_size,
                              hipStream_t stream) {
    const float* q_input = (const float*)d_in[0];
    const void*  mask    = d_in[1];
    const float* w_qkv   = (const float*)d_in[2];
    const float* b_qkv   = (const float*)d_in[3];
    const float* w_out   = (const float*)d_in[4];
    const float* b_out   = (const float*)d_in[5];
    float* out = (float*)d_out;
    char* ws = (char*)d_ws;

    const size_t FUSED_WS = 42991616;   // through mbits
    const size_t SPLIT_WS = 60293120;   // + Opart (2x8.4MB bf16) + lpart (2x256KB)

    if (ws_size >= FUSED_WS) {
        bf16*           qkv     = (bf16*)ws;                               // 25165824
        unsigned short* qin_bf  = (unsigned short*)(ws + 25165824);        // 8388608 (reused as ctx)
        unsigned short* ctx     = qin_bf;
        unsigned short* wqkv_bt = (unsigned short*)(ws + 33554432);        // 6291456
        unsigned short* wout_bt = (unsigned short*)(ws + 39845888);        // 2097152
        unsigned*       mbits   = (unsigned*)(ws + 41943040);              // 1048576

        prep_kernel<<<7172, 256, 0, stream>>>(q_input, mask, w_qkv, w_out, b_out,
                                              qin_bf, wqkv_bt, wout_bt, mbits,
                                              out + (size_t)M_DIM * H_DIM);
        gemm_bt_kernel<128, 128, true, true><<<dim3(24, 32), 256, 0, stream>>>(qin_bf, wqkv_bt, b_qkv, qkv, 3072);

        if (ws_size >= SPLIT_WS) {
            unsigned short* Opart = (unsigned short*)(ws + 42991616);      // 2 x 8388608
            float*          lpart = (float*)(ws + 59768832);               // 2 x 262144
            attn_mfma_kernel<true><<<dim3(16, 32, 2), 512, 0, stream>>>(qkv, mbits, Opart, lpart);
            combine_kernel<<<2048, 256, 0, stream>>>(Opart, lpart, ctx);
        } else {
            attn_mfma_kernel<false><<<dim3(16, 32), 512, 0, stream>>>(qkv, mbits, ctx, nullptr);
        }
        gemm_bt_kernel<64, 128, false, false><<<dim3(8, 64), 256, 0, stream>>>(ctx, wout_bt, nullptr, out, 1024);
    } else {
        // R9-proven fallback layout (peak ~40.9 MB), separate prep kernels
        bf16*           qkv     = (bf16*)ws;                               // 25165824
        unsigned short* qin_bf  = (unsigned short*)(ws + 25165824);        // 8388608 (reused as ctx)
        unsigned short* ctx     = qin_bf;
        unsigned short* wqkv_bt = (unsigned short*)(ws + 33554432);        // 6291456 (reused as wout_bt)
        unsigned short* wout_bt = wqkv_bt;
        unsigned*       mbits   = (unsigned*)(ws + 39845888);              // 1048576
        int*            flag    = (int*)(ws + 40894464);                   // 4

        detect_mask_kernel<<<1, 256, 0, stream>>>((const int*)mask, flag);
        pack_mask_kernel<<<1024, 256, 0, stream>>>((const int*)mask, (const unsigned char*)mask, flag, mbits);
        convert_kernel<<<2048, 256, 0, stream>>>(q_input, qin_bf);
        transpose_bf16_kernel<<<dim3(96, 32), 256, 0, stream>>>(w_qkv, wqkv_bt, 1024, 3072);
        gemm_bt_kernel<128, 128, true, true><<<dim3(24, 32), 256, 0, stream>>>(qin_bf, wqkv_bt, b_qkv, qkv, 3072);
        transpose_bf16_kernel<<<dim3(32, 32), 256, 0, stream>>>(w_out, wout_bt, 1024, 1024);
        attn_mfma_kernel<false><<<dim3(16, 32), 512, 0, stream>>>(qkv, mbits, ctx, nullptr);
        gemm_bt_kernel<64, 128, false, false><<<dim3(8, 64), 256, 0, stream>>>(ctx, wout_bt, nullptr, out, 1024);
        bout_copy_kernel<<<4, 256, 0, stream>>>(b_out, out + (size_t)M_DIM * H_DIM);
    }
}

// Round 12
// 238.458 us; speedup vs baseline: 1.0960x; 1.0960x over previous
//
#include <hip/hip_runtime.h>
#include <hip/hip_bf16.h>
#include <math.h>

// Problem constants
#define F_DIM 2048
#define B_DIM 2
#define H_DIM 1024
#define N_HEADS 16
#define E_DIM 64
#define D3 3072          // 3*H
#define M_DIM 4096       // F*B

typedef __hip_bfloat16 bf16;
typedef __attribute__((ext_vector_type(8))) __bf16 bf16x8;
typedef __attribute__((ext_vector_type(8))) unsigned short u16x8;
typedef __attribute__((ext_vector_type(4))) float f32x4;

// float -> bf16 bits, round-to-nearest-even
static __device__ __forceinline__ unsigned short f2bf(float f) {
    unsigned u = __float_as_uint(f);
    return (unsigned short)((u + 0x7FFFu + ((u >> 16) & 1u)) >> 16);
}

// pack two floats to bf16x2 (RNE); HW packed convert when available
static __device__ __forceinline__ unsigned pk_bf16(float a, float b) {
#if __has_builtin(__builtin_amdgcn_cvt_pk_bf16_f32)
    typedef __attribute__((ext_vector_type(2))) __bf16 bf16x2;
    bf16x2 v = __builtin_amdgcn_cvt_pk_bf16_f32(a, b);
    unsigned u; __builtin_memcpy(&u, &v, 4); return u;
#else
    return (unsigned)f2bf(a) | ((unsigned)f2bf(b) << 16);
#endif
}

// async global->LDS, 16B per lane; lds ptr must be wave-uniform base
static __device__ __forceinline__ void glds16(const unsigned short* g, unsigned short* l) {
    __builtin_amdgcn_global_load_lds((const __attribute__((address_space(1))) unsigned int*)g,
                                     (__attribute__((address_space(3))) unsigned int*)l,
                                     16, 0, 0);
}

// 0.125 * log2(e): folded into q at QKV-gemm epilogue so softmax is exp2(S)
#define Q_SCALE 0.18033688011112042f

// ---------------------------------------------------------------------------
// Fused prep (R10-proven)
// ---------------------------------------------------------------------------
__global__ __launch_bounds__(256) void prep_kernel(const float* __restrict__ q_input,
                                                   const void* __restrict__ mask,
                                                   const float* __restrict__ w_qkv,
                                                   const float* __restrict__ w_out,
                                                   const float* __restrict__ b_out,
                                                   unsigned short* __restrict__ qin_bf,
                                                   unsigned short* __restrict__ wqkv_bt,
                                                   unsigned short* __restrict__ wout_bt,
                                                   unsigned* __restrict__ mbits,
                                                   float* __restrict__ bout_dst) {
    __shared__ float sh[32 * 33];
    const int bid = blockIdx.x;
    const int tid = threadIdx.x;

    if (bid < 2048) {                       // convert
        int i = (bid * 256 + tid) * 8;
        float4 a = *(const float4*)&q_input[i];
        float4 b = *(const float4*)&q_input[i + 4];
        u16x8 o;
        o[0] = f2bf(a.x); o[1] = f2bf(a.y); o[2] = f2bf(a.z); o[3] = f2bf(a.w);
        o[4] = f2bf(b.x); o[5] = f2bf(b.y); o[6] = f2bf(b.z); o[7] = f2bf(b.w);
        *(u16x8*)&qin_bf[i] = o;
    } else if (bid < 6144) {                // transposes
        const float* in; unsigned short* out; int R, C, bx, by;
        if (bid < 5120) { int idx = bid - 2048; in = w_qkv; out = wqkv_bt; R = 1024; C = 3072; bx = idx % 96; by = idx / 96; }
        else            { int idx = bid - 5120; in = w_out; out = wout_bt; R = 1024; C = 1024; bx = idx % 32; by = idx / 32; }
        float (*t)[33] = (float(*)[33])sh;
        const int c0 = bx * 32, r0 = by * 32;
        const int lc = tid & 31, lr = tid >> 5;
        #pragma unroll
        for (int i = 0; i < 4; ++i) {
            int r = lr + i * 8;
            t[r][lc] = in[(size_t)(r0 + r) * C + c0 + lc];
        }
        __syncthreads();
        #pragma unroll
        for (int i = 0; i < 4; ++i) {
            int r = lr + i * 8;
            out[(size_t)(c0 + r) * R + r0 + lc] = f2bf(t[lc][r]);
        }
    } else if (bid < 7168) {                // mask pack with inline detect
        int* shi = (int*)sh;
        int v = ((const int*)mask)[tid] & ~1;
        unsigned long long bal = __ballot(v != 0);
        if ((tid & 63) == 0) shi[tid >> 6] = (bal != 0) ? 1 : 0;
        __syncthreads();
        const int byte_mode = shi[0] | shi[1] | shi[2] | shi[3];
        int w = (bid - 6144) * 256 + tid;
        size_t base = (size_t)w * 32;
        unsigned out = 0;
        if (byte_mode) {
            const unsigned char* mu = (const unsigned char*)mask;
            #pragma unroll
            for (int j = 0; j < 32; ++j) out |= (mu[base + j] ? 1u : 0u) << j;
        } else {
            const int* mi = (const int*)mask;
            #pragma unroll
            for (int j = 0; j < 32; ++j) out |= (mi[base + j] ? 1u : 0u) << j;
        }
        mbits[w] = out;
    } else {                                // b_out copy
        int h = (bid - 7168) * 256 + tid;
        if (h < H_DIM) bout_dst[h] = b_out[h];
    }
}

// --------------------- fallback prep kernels (R9-proven) -------------------
__global__ void detect_mask_kernel(const int* __restrict__ mask_words, int* __restrict__ flag) {
    __shared__ int red[256];
    int v = mask_words[threadIdx.x];
    red[threadIdx.x] = v & ~1;
    __syncthreads();
    for (int s = 128; s > 0; s >>= 1) {
        if (threadIdx.x < s) red[threadIdx.x] |= red[threadIdx.x + s];
        __syncthreads();
    }
    if (threadIdx.x == 0) *flag = (red[0] != 0) ? 1 : 0;
}

__global__ void pack_mask_kernel(const int* __restrict__ mi, const unsigned char* __restrict__ mu,
                                 const int* __restrict__ flag, unsigned* __restrict__ bits) {
    int w = blockIdx.x * 256 + threadIdx.x;
    size_t base = (size_t)w * 32;
    unsigned out = 0;
    if (*flag) {
        #pragma unroll
        for (int j = 0; j < 32; ++j) out |= (mu[base + j] ? 1u : 0u) << j;
    } else {
        #pragma unroll
        for (int j = 0; j < 32; ++j) out |= (mi[base + j] ? 1u : 0u) << j;
    }
    bits[w] = out;
}

__global__ __launch_bounds__(256) void convert_kernel(const float* __restrict__ in,
                                                      unsigned short* __restrict__ out) {
    int i = (blockIdx.x * 256 + threadIdx.x) * 8;
    float4 a = *(const float4*)&in[i];
    float4 b = *(const float4*)&in[i + 4];
    u16x8 o;
    o[0] = f2bf(a.x); o[1] = f2bf(a.y); o[2] = f2bf(a.z); o[3] = f2bf(a.w);
    o[4] = f2bf(b.x); o[5] = f2bf(b.y); o[6] = f2bf(b.z); o[7] = f2bf(b.w);
    *(u16x8*)&out[i] = o;
}

__global__ __launch_bounds__(256) void transpose_bf16_kernel(const float* __restrict__ in,
                                                             unsigned short* __restrict__ out,
                                                             int R, int C) {
    __shared__ float t[32][33];
    const int c0 = blockIdx.x * 32, r0 = blockIdx.y * 32;
    const int lc = threadIdx.x & 31, lr = threadIdx.x >> 5;
    #pragma unroll
    for (int i = 0; i < 4; ++i) {
        int r = lr + i * 8;
        t[r][lc] = in[(size_t)(r0 + r) * C + c0 + lc];
    }
    __syncthreads();
    #pragma unroll
    for (int i = 0; i < 4; ++i) {
        int r = lr + i * 8;
        out[(size_t)(c0 + r) * R + r0 + lc] = f2bf(t[lc][r]);
    }
}

__global__ void bout_copy_kernel(const float* __restrict__ b_out, float* __restrict__ dst) {
    int h = blockIdx.x * 256 + threadIdx.x;
    if (h < H_DIM) dst[h] = b_out[h];
}

// ---------------------------------------------------------------------------
// m97-style bf16 MFMA GEMM, B-transposed input, tile BM x BN (mult of 64).
// SCALE_Q: multiply q-columns (col%192 < 64) by Q_SCALE in the epilogue
// (folds the attention 1/sqrt(E) and log2(e) into Q once).
// ---------------------------------------------------------------------------
template<int BM, int BN, bool ADD_BIAS, bool OUT_BF16, bool SCALE_Q>
__global__ __launch_bounds__(256) void gemm_bt_kernel(const unsigned short* __restrict__ A,
                                                      const unsigned short* __restrict__ Bt,
                                                      const float* __restrict__ bias,
                                                      void* __restrict__ Cout, int Nc) {
    __shared__ unsigned short Ald[BM * 32];
    __shared__ unsigned short Bld[BN * 32];
    constexpr int WM = BM / 2, WN = BN / 2;
    constexpr int MI = WM / 16, NI = WN / 16;
    constexpr int ACH = BM * 4;
    constexpr int TCH = (BM + BN) * 4;
    const int tid = threadIdx.x;
    const int wave = tid >> 6;
    const int lane = tid & 63;
    const int quad = lane >> 4;
    const int l16 = lane & 15;
    const int wm = (wave & 1) * WM;
    const int wn = (wave >> 1) * WN;
    const int m0 = blockIdx.y * BM;
    const int n0 = blockIdx.x * BN;

    f32x4 acc[MI][NI];
    #pragma unroll
    for (int i = 0; i < MI; ++i)
        #pragma unroll
        for (int j = 0; j < NI; ++j) acc[i][j] = (f32x4){0.f, 0.f, 0.f, 0.f};

    for (int k0 = 0; k0 < 1024; k0 += 32) {
        __syncthreads();
        #pragma unroll
        for (int rr = 0; rr < TCH / 256; ++rr) {
            const int chunk = rr * 256 + tid;
            const int wbase = (rr * 256 + wave * 64) * 8;
            if (chunk < ACH) {
                const int row = chunk >> 2, ko = (chunk & 3) * 8;
                glds16(&A[(size_t)(m0 + row) * 1024 + k0 + ko], &Ald[wbase]);
            } else {
                const int c2 = chunk - ACH;
                const int row = c2 >> 2, ko = (c2 & 3) * 8;
                glds16(&Bt[(size_t)(n0 + row) * 1024 + k0 + ko], &Bld[wbase - ACH * 8]);
            }
        }
        __syncthreads();

        bf16x8 af[MI], bfr[NI];
        #pragma unroll
        for (int i = 0; i < MI; ++i)
            af[i] = *(const bf16x8*)&Ald[(wm + i * 16 + l16) * 32 + quad * 8];
        #pragma unroll
        for (int j = 0; j < NI; ++j)
            bfr[j] = *(const bf16x8*)&Bld[(wn + j * 16 + l16) * 32 + quad * 8];
        #pragma unroll
        for (int mi = 0; mi < MI; ++mi)
            #pragma unroll
            for (int ni = 0; ni < NI; ++ni)
                acc[mi][ni] = __builtin_amdgcn_mfma_f32_16x16x32_bf16(af[mi], bfr[ni], acc[mi][ni], 0, 0, 0);
    }

    #pragma unroll
    for (int ni = 0; ni < NI; ++ni) {
        const int col = n0 + wn + ni * 16 + l16;
        const float bv = ADD_BIAS ? bias[col] : 0.f;
        const bool scale = SCALE_Q && ((col % 192) < 64);
        #pragma unroll
        for (int mi = 0; mi < MI; ++mi) {
            const int rowb = m0 + wm + mi * 16 + quad * 4;
            #pragma unroll
            for (int r = 0; r < 4; ++r) {
                float v = acc[mi][ni][r] + bv;
                if (SCALE_Q) v = scale ? v * Q_SCALE : v;
                if (OUT_BF16) ((unsigned short*)Cout)[(size_t)(rowb + r) * Nc + col] = f2bf(v);
                else          ((float*)Cout)[(size_t)(rowb + r) * Nc + col] = v;
            }
        }
    }
}

// ---------------------------------------------------------------------------
// MFMA flash attention (R10-proven structure), fixed-max softmax with the
// scale pre-folded into Q (exp2(S) directly). 128 Q-rows/block, 512 threads.
// ---------------------------------------------------------------------------
#define LSTR 72        // LDS row stride (elements) for K, Vt, and P
__global__ __launch_bounds__(512) void attn_mfma_kernel(const bf16* __restrict__ qkv_,
                                                        const unsigned* __restrict__ mbits,
                                                        unsigned short* __restrict__ ctxb) {
    __shared__ unsigned short K_lds[64 * LSTR];        // [t][e]      9216 B
    __shared__ unsigned short Vt_lds[64 * LSTR];       // [e][slot]   9216 B
    __shared__ unsigned short P_lds[128 * LSTR];       // [row][slot] 18432 B

    const unsigned short* qkv = (const unsigned short*)qkv_;
    const int tid = threadIdx.x;
    const int wave = tid >> 6;          // 0..7
    const int lane = tid & 63;
    const int quad = lane >> 4;
    const int l16 = lane & 15;
    const int f0 = blockIdx.x * 128;
    const int b = blockIdx.y >> 4;
    const int n = blockIdx.y & 15;
    const int head = n * 192;

    // Q fragments [ks] (A layout): rows f0 + wave*16 + l16 (pre-scaled)
    bf16x8 qf[2];
    #pragma unroll
    for (int ks = 0; ks < 2; ++ks) {
        int f = f0 + wave * 16 + l16;
        qf[ks] = *(const bf16x8*)&qkv[(size_t)(f * B_DIM + b) * D3 + head + ks * 32 + quad * 8];
    }

    f32x4 O[4];
    #pragma unroll
    for (int ec = 0; ec < 4; ++ec) O[ec] = (f32x4){0.f, 0.f, 0.f, 0.f};
    float lsum[4] = {0.f, 0.f, 0.f, 0.f};

    unsigned short* Pw = P_lds + wave * 16 * LSTR;

    for (int t0 = 0; t0 < F_DIM; t0 += 64) {
        __syncthreads();   // previous tile's LDS reads complete

        // stage K tile [64][64] row-major: 512 chunks, 1/thread
        {
            int tr = tid >> 3, e0 = (tid & 7) * 8;
            u16x8 kv = *(const u16x8*)&qkv[(size_t)((t0 + tr) * B_DIM + b) * D3 + head + 64 + e0];
            *(u16x8*)&K_lds[tr * LSTR + e0] = kv;
        }
        // stage V transposed with (t, t+16) interleave: slot h*32+2u(+o).
        if (tid < 256) {
            int u = tid & 15, h = (tid >> 4) & 1, e0 = (tid >> 5) * 8;
            int ta = t0 + h * 32 + u;
            u16x8 v0 = *(const u16x8*)&qkv[(size_t)(ta * B_DIM + b) * D3 + head + 128 + e0];
            u16x8 v1 = *(const u16x8*)&qkv[(size_t)((ta + 16) * B_DIM + b) * D3 + head + 128 + e0];
            #pragma unroll
            for (int j = 0; j < 8; ++j) {
                unsigned pk = (unsigned)v0[j] | ((unsigned)v1[j] << 16);
                *(unsigned*)&Vt_lds[(e0 + j) * LSTR + h * 32 + 2 * u] = pk;
            }
        }
        __syncthreads();   // staging visible

        // S = Q . K^T  [16 x 64] per wave; S[ck] covers t = ck*16 + l16
        f32x4 S[4];
        #pragma unroll
        for (int ck = 0; ck < 4; ++ck) S[ck] = (f32x4){0.f, 0.f, 0.f, 0.f};
        #pragma unroll
        for (int ck = 0; ck < 4; ++ck) {
            bf16x8 kb0 = *(const bf16x8*)&K_lds[(ck * 16 + l16) * LSTR + quad * 8];
            bf16x8 kb1 = *(const bf16x8*)&K_lds[(ck * 16 + l16) * LSTR + 32 + quad * 8];
            S[ck] = __builtin_amdgcn_mfma_f32_16x16x32_bf16(qf[0], kb0, S[ck], 0, 0, 0);
            S[ck] = __builtin_amdgcn_mfma_f32_16x16x32_bf16(qf[1], kb1, S[ck], 0, 0, 0);
        }

        // fixed-max softmax: p = mask ? exp2(S) : 0 (scale folded into Q);
        // packed P writes: (p0,p1) -> slots (2*l16, 2*l16+1); (p2,p3) -> +32.
        #pragma unroll
        for (int r = 0; r < 4; ++r) {
            const int row = quad * 4 + r;            // within wave's 16 rows
            const int f = f0 + wave * 16 + row;
            uint2 wb = *(const uint2*)&mbits[((size_t)b * F_DIM + f) * 64 + (t0 >> 5)];
            float p[4];
            #pragma unroll
            for (int ck = 0; ck < 4; ++ck) {
                unsigned wsel = (ck & 2) ? wb.y : wb.x;
                int bit = ((ck & 1) << 4) + l16;
                float pv = __builtin_amdgcn_exp2f(S[ck][r]);
                p[ck] = ((wsel >> bit) & 1u) ? pv : 0.f;
            }
            lsum[r] += (p[0] + p[1]) + (p[2] + p[3]);
            *(unsigned*)&Pw[row * LSTR + 2 * l16] = pk_bf16(p[0], p[1]);
            *(unsigned*)&Pw[row * LSTR + 32 + 2 * l16] = pk_bf16(p[2], p[3]);
        }

        // O += P . V  (both operands traverse slots in identical order)
        #pragma unroll
        for (int ks = 0; ks < 2; ++ks) {
            bf16x8 pa = *(const bf16x8*)&Pw[l16 * LSTR + ks * 32 + quad * 8];
            #pragma unroll
            for (int ec = 0; ec < 4; ++ec) {
                bf16x8 vb = *(const bf16x8*)&Vt_lds[(ec * 16 + l16) * LSTR + ks * 32 + quad * 8];
                O[ec] = __builtin_amdgcn_mfma_f32_16x16x32_bf16(pa, vb, O[ec], 0, 0, 0);
            }
        }
    }

    // epilogue: reduce l over the 16 lanes sharing each row, write ctx (bf16)
    #pragma unroll
    for (int r = 0; r < 4; ++r) {
        float l = lsum[r];
        #pragma unroll
        for (int d = 1; d < 16; d <<= 1) l += __shfl_xor(l, d);
        const int f = f0 + wave * 16 + quad * 4 + r;
        const float inv = 1.0f / l;
        #pragma unroll
        for (int ec = 0; ec < 4; ++ec) {
            ctxb[(size_t)(f * B_DIM + b) * H_DIM + n * 64 + ec * 16 + l16] = f2bf(O[ec][r] * inv);
        }
    }
}

// ---------------------------------------------------------------------------
extern "C" void kernel_launch(void* const* d_in, const int* in_sizes, int n_in,
                              void* d_out, int out_size, void* d_ws, size_t ws_size,
                              hipStream_t stream) {
    const float* q_input = (const float*)d_in[0];
    const void*  mask    = d_in[1];
    const float* w_qkv   = (const float*)d_in[2];
    const float* b_qkv   = (const float*)d_in[3];
    const float* w_out   = (const float*)d_in[4];
    const float* b_out   = (const float*)d_in[5];
    float* out = (float*)d_out;
    char* ws = (char*)d_ws;

    const size_t FUSED_WS = 42991616;   // through mbits

    if (ws_size >= FUSED_WS) {
        bf16*           qkv     = (bf16*)ws;                               // 25165824
        unsigned short* qin_bf  = (unsigned short*)(ws + 25165824);        // 8388608 (reused as ctx)
        unsigned short* ctx     = qin_bf;
        unsigned short* wqkv_bt = (unsigned short*)(ws + 33554432);        // 6291456
        unsigned short* wout_bt = (unsigned short*)(ws + 39845888);        // 2097152
        unsigned*       mbits   = (unsigned*)(ws + 41943040);              // 1048576

        prep_kernel<<<7172, 256, 0, stream>>>(q_input, mask, w_qkv, w_out, b_out,
                                              qin_bf, wqkv_bt, wout_bt, mbits,
                                              out + (size_t)M_DIM * H_DIM);
        gemm_bt_kernel<128, 128, true, true, true><<<dim3(24, 32), 256, 0, stream>>>(qin_bf, wqkv_bt, b_qkv, qkv, 3072);
        attn_mfma_kernel<<<dim3(16, 32), 512, 0, stream>>>(qkv, mbits, ctx);
        gemm_bt_kernel<64, 128, false, false, false><<<dim3(8, 64), 256, 0, stream>>>(ctx, wout_bt, nullptr, out, 1024);
    } else {
        // R9-proven fallback layout (peak ~40.9 MB), separate prep kernels
        bf16*           qkv     = (bf16*)ws;                               // 25165824
        unsigned short* qin_bf  = (unsigned short*)(ws + 25165824);        // 8388608 (reused as ctx)
        unsigned short* ctx     = qin_bf;
        unsigned short* wqkv_bt = (unsigned short*)(ws + 33554432);        // 6291456 (reused as wout_bt)
        unsigned short* wout_bt = wqkv_bt;
        unsigned*       mbits   = (unsigned*)(ws + 39845888);              // 1048576
        int*            flag    = (int*)(ws + 40894464);                   // 4

        detect_mask_kernel<<<1, 256, 0, stream>>>((const int*)mask, flag);
        pack_mask_kernel<<<1024, 256, 0, stream>>>((const int*)mask, (const unsigned char*)mask, flag, mbits);
        convert_kernel<<<2048, 256, 0, stream>>>(q_input, qin_bf);
        transpose_bf16_kernel<<<dim3(96, 32), 256, 0, stream>>>(w_qkv, wqkv_bt, 1024, 3072);
        gemm_bt_kernel<128, 128, true, true, true><<<dim3(24, 32), 256, 0, stream>>>(qin_bf, wqkv_bt, b_qkv, qkv, 3072);
        transpose_bf16_kernel<<<dim3(32, 32), 256, 0, stream>>>(w_out, wout_bt, 1024, 1024);
        attn_mfma_kernel<<<dim3(16, 32), 512, 0, stream>>>(qkv, mbits, ctx);
        gemm_bt_kernel<64, 128, false, false, false><<<dim3(8, 64), 256, 0, stream>>>(ctx, wout_bt, nullptr, out, 1024);
        bout_copy_kernel<<<4, 256, 0, stream>>>(b_out, out + (size_t)M_DIM * H_DIM);
    }
}